// Round 5
// baseline (339.532 us; speedup 1.0000x reference)
//
#include <hip/hip_runtime.h>

// Problem constants (B,T,D,H from reference)
#define B_  4
#define T_  2048
#define D_  1024
#define H_  16
#define HD_ 64
#define BT_ (B_*T_)   // 8192
#define K_  D_        // 1024 (GEMM inner dim)

typedef unsigned short u16;
typedef unsigned int   u32;

typedef __attribute__((ext_vector_type(8))) short bf16x8;  // 8 bf16 (4 VGPRs)
typedef __attribute__((ext_vector_type(4))) float f32x4;   // MFMA 16x16 C/D

__device__ __forceinline__ u16 f2bf(float f) {
  u32 u = __builtin_bit_cast(u32, f);
  u += 0x7fffu + ((u >> 16) & 1u);   // round-to-nearest-even
  return (u16)(u >> 16);
}

__device__ __forceinline__ u32 pack2bf(float a, float b) {
  u32 ua = __builtin_bit_cast(u32, a) + 0x8000u;
  u32 ub = __builtin_bit_cast(u32, b) + 0x8000u;
  return (ub & 0xFFFF0000u) | (ua >> 16);
}

#define GLOAD_LDS16(g, l) __builtin_amdgcn_global_load_lds(                  \
    (const __attribute__((address_space(1))) void*)(g),                      \
    (__attribute__((address_space(3))) void*)(l), 16, 0, 0)

// compiler-only memory barrier: forbids IR reordering of LDS/global ops
#define MEMBAR() __asm__ volatile("" ::: "memory")
#define SCHEDB() __builtin_amdgcn_sched_barrier(0)
#define SBAR()   __builtin_amdgcn_s_barrier()

#define SFC 0.18033688011f   /* 0.125 * log2(e); folded into Q projection */

// ---------------- fp32 -> bf16 elementwise converts ---------------------------
__global__ __launch_bounds__(256) void cvt3_f32_bf16(
    const float* __restrict__ i0, const float* __restrict__ i1,
    const float* __restrict__ i2,
    u16* __restrict__ o0, u16* __restrict__ o1, u16* __restrict__ o2,
    int cvx) {
  const int blk = blockIdx.x;
  const int seg = (blk >= 2*cvx) ? 2 : (blk >= cvx ? 1 : 0);
  const int ib  = blk - seg*cvx;
  const float* in = seg==0 ? i0 : (seg==1 ? i1 : i2);
  u16* out        = seg==0 ? o0 : (seg==1 ? o1 : o2);
  const int i = ib*256 + threadIdx.x;
  float4 x = ((const float4*)in)[i];
  u32 lo = (u32)f2bf(x.x) | ((u32)f2bf(x.y) << 16);
  u32 hi = (u32)f2bf(x.z) | ((u32)f2bf(x.w) << 16);
  ((uint2*)out)[i] = make_uint2(lo, hi);
}

__global__ __launch_bounds__(256) void cvt4_f32_bf16(
    const float* __restrict__ i0, const float* __restrict__ i1,
    const float* __restrict__ i2, const float* __restrict__ i3,
    u16* __restrict__ o0, u16* __restrict__ o1,
    u16* __restrict__ o2, u16* __restrict__ o3, int cvw) {
  const int blk = blockIdx.x;
  const int seg = blk / cvw;           // 0..3
  const int ib  = blk - seg*cvw;
  const float* in = seg==0 ? i0 : (seg==1 ? i1 : (seg==2 ? i2 : i3));
  u16* out        = seg==0 ? o0 : (seg==1 ? o1 : (seg==2 ? o2 : o3));
  const int i = ib*256 + threadIdx.x;
  float4 x = ((const float4*)in)[i];
  u32 lo = (u32)f2bf(x.x) | ((u32)f2bf(x.y) << 16);
  u32 hi = (u32)f2bf(x.z) | ((u32)f2bf(x.w) << 16);
  ((uint2*)out)[i] = make_uint2(lo, hi);
}

// ---------------- GEMM: 256x128 tile, BK=64, 2-subphase counted pipeline ------
// 512 threads = 8 waves (4M x 2N), per-wave 64x64 output (acc[4][4]).
// LDS 112KB: A double-buffered (2 x 32KB) + B TRIPLE-buffered (3 x 16KB).
// Per K-tile, two k-half subphases, each {8 ds_read_b128 | stage issues ->
// lgkmcnt(0) -> setprio(1) 16 MFMA setprio(0)}; ONE barrier per K-tile with
// s_waitcnt vmcnt(2): A(t+1) issued in ph1 (ages ~1.5 phases), B(t+1) issued
// LAST tile (ages a full tile), only B(t+2) stays in flight.  Never a vmcnt(0)
// drain except the last two iterations.
// 8-slot XOR swizzle: physical 16B slot s of row r holds k-chunk s ^ (r&7);
// staging global source pre-swizzled per-lane (rule 21), frag ds_read applies
// the same XOR -> 2 lanes/slot per 16-lane quarter (free).
// Operands swapped (W-frag first): lane regs hold 4 consecutive n.
// seg = blockIdx.x>>8 selects {A,W,bias,Out}: QKV grid 768 = 3x256 (1/CU per
// segment); O-projection grid 256.  seg==2 writes V transposed to Vt[bh,hd,t].
template<bool OUT_BF16>
__global__ __launch_bounds__(512, 2) void gemm_big(
    const u16* __restrict__ A0, const u16* __restrict__ A1,
    const u16* __restrict__ A2,
    const u16* __restrict__ W0, const u16* __restrict__ W1,
    const u16* __restrict__ W2,
    const float* __restrict__ b0, const float* __restrict__ b1,
    const float* __restrict__ b2,
    void* __restrict__ O0, void* __restrict__ O1, void* __restrict__ O2,
    float osc0)
{
  __shared__ u16 As[2][256 * 64];   // 64 KB  [buf][row][slot][8]
  __shared__ u16 Bs[3][128 * 64];   // 48 KB

  const int tid  = threadIdx.x;
  const int wave = tid >> 6;
  const int lane = tid & 63;
  const int col  = lane & 15;
  const int quad = lane >> 4;
  const int wm   = wave >> 1;          // 0..3 (64-row band)
  const int wn   = wave & 1;           // 0..1 (64-col band)

  const int seg   = blockIdx.x >> 8;   // 0=Q 1=K 2=V (0 for O-proj)
  const int inner = blockIdx.x & 255;
  const u16*  A    = seg==0 ? A0 : (seg==1 ? A1 : A2);
  const u16*  W    = seg==0 ? W0 : (seg==1 ? W1 : W2);
  const float* bias = seg==0 ? b0 : (seg==1 ? b1 : b2);
  void*       Out  = seg==0 ? O0 : (seg==1 ? O1 : O2);
  const float oscale = (seg == 0) ? osc0 : 1.0f;

  // XCD-clustered: each XCD owns 4 m-panels x all 8 n-tiles (A 2MB + W 2MB L2)
  const int xcd = inner & 7;
  const int jj  = inner >> 3;          // 0..31
  const int m0 = (xcd*4 + (jj & 3)) * 256;
  const int n0 = (jj >> 2) * 128;

  // staging maps: one issue = 512 thr x 16B = 64 rows x 128B.
  // thread: row-in-chunk = tid>>3, slot = tid&7, global k-chunk = slot^(row&7)
  // (chunk bases are 64-row aligned so row&7 == (tid>>3)&7 for all chunks)
  const int srow = tid >> 3;                        // 0..63
  const int ksw  = ((tid & 7) ^ (srow & 7)) * 8;
  const u16* agp = A + (size_t)(m0 + srow) * K_ + ksw;
  const u16* bgp = W + (size_t)(n0 + srow) * K_ + ksw;
  u16* const adst = (u16*)As + tid * 8;   // + buf*16384 + rb*64
  u16* const bdst = (u16*)Bs + tid * 8;   // + bq*8192  + rb*64

#define ISS_A(buf, rb, k0) GLOAD_LDS16(agp + (size_t)(rb)*K_ + (k0),          \
                                       adst + (buf)*16384 + (rb)*64)
#define ISS_B(bq, rb, k0)  GLOAD_LDS16(bgp + (size_t)(rb)*K_ + (k0),          \
                                       bdst + (bq)*8192 + (rb)*64)

  f32x4 acc[4][4];
  const f32x4 z = {0.f, 0.f, 0.f, 0.f};
#pragma unroll
  for (int i = 0; i < 4; ++i)
#pragma unroll
    for (int j = 0; j < 4; ++j) acc[i][j] = z;

  // frag LDS offsets (u16): row*64 + ((kh*4+quad) ^ (row&7))*8
  u32 aro[4][2], bro[4][2];
#pragma unroll
  for (int i = 0; i < 4; ++i) {
    const int ar = wm*64 + i*16 + col;
    const int br = wn*64 + i*16 + col;
#pragma unroll
    for (int kh = 0; kh < 2; ++kh) {
      aro[i][kh] = (u32)(ar*64 + (((kh*4 + quad) ^ (ar & 7)) * 8));
      bro[i][kh] = (u32)(br*64 + (((kh*4 + quad) ^ (br & 7)) * 8));
    }
  }

  // prologue: tile0 (A buf0, B buf0) + B(t1 -> buf1); counted wait
  ISS_A(0, 0, 0); ISS_A(0, 64, 0); ISS_A(0, 128, 0); ISS_A(0, 192, 0);
  ISS_B(0, 0, 0); ISS_B(0, 64, 0);
  ISS_B(1, 0, 64); ISS_B(1, 64, 64);
  MEMBAR();
  __asm__ volatile("s_waitcnt vmcnt(2)" ::: "memory");   // tile0 landed
  SCHEDB();
  SBAR();
  MEMBAR();

  int bq = 0;                       // B buffer of current tile (t%3)
  for (int t = 0; t < 16; ++t) {
    const int pA = t & 1;
    const u16* Ab = (const u16*)As + pA * 16384;
    const u16* Bb = (const u16*)Bs + bq * 8192;
    const int kn = (t + 1) * 64;
    const int k2 = (t + 2) * 64;
    const int b2 = (bq >= 1) ? bq - 1 : 2;   // (t+2)%3

    // ---- subphase kh=0 ----------------------------------------------------
    if (t < 15) { ISS_A(pA ^ 1, 0, kn); ISS_A(pA ^ 1, 64, kn); }
    MEMBAR();
    bf16x8 af0[4], bf0[4];
#pragma unroll
    for (int i = 0; i < 4; ++i) af0[i] = *(const bf16x8*)(Ab + aro[i][0]);
#pragma unroll
    for (int i = 0; i < 4; ++i) bf0[i] = *(const bf16x8*)(Bb + bro[i][0]);
    if (t < 15) { ISS_A(pA ^ 1, 128, kn); ISS_A(pA ^ 1, 192, kn); }
    MEMBAR();
    __asm__ volatile("s_waitcnt lgkmcnt(0)" ::: "memory");
    SCHEDB();
    __builtin_amdgcn_s_setprio(1);
#pragma unroll
    for (int mt = 0; mt < 4; ++mt)
#pragma unroll
      for (int nt = 0; nt < 4; ++nt)
        acc[mt][nt] = __builtin_amdgcn_mfma_f32_16x16x32_bf16(
            bf0[nt], af0[mt], acc[mt][nt], 0, 0, 0);
    __builtin_amdgcn_s_setprio(0);

    // ---- subphase kh=1 ----------------------------------------------------
    if (t < 14) { ISS_B(b2, 0, k2); ISS_B(b2, 64, k2); }
    MEMBAR();
    bf16x8 af1[4], bf1[4];
#pragma unroll
    for (int i = 0; i < 4; ++i) af1[i] = *(const bf16x8*)(Ab + aro[i][1]);
#pragma unroll
    for (int i = 0; i < 4; ++i) bf1[i] = *(const bf16x8*)(Bb + bro[i][1]);
    __asm__ volatile("s_waitcnt lgkmcnt(0)" ::: "memory");
    SCHEDB();
    __builtin_amdgcn_s_setprio(1);
#pragma unroll
    for (int mt = 0; mt < 4; ++mt)
#pragma unroll
      for (int nt = 0; nt < 4; ++nt)
        acc[mt][nt] = __builtin_amdgcn_mfma_f32_16x16x32_bf16(
            bf1[nt], af1[mt], acc[mt][nt], 0, 0, 0);
    __builtin_amdgcn_s_setprio(0);
    SCHEDB();

    // boundary: tile t+1 (A + B) landed; only B(t+2)'s 2 loads stay in flight
    if (t < 14) { __asm__ volatile("s_waitcnt vmcnt(2)" ::: "memory"); }
    else        { __asm__ volatile("s_waitcnt vmcnt(0)" ::: "memory"); }
    SCHEDB();
    SBAR();
    MEMBAR();
    bq = (bq >= 2) ? 0 : bq + 1;
  }
#undef ISS_A
#undef ISS_B

  // epilogue: lane holds 4 consecutive n per (mt,nt)
#pragma unroll
  for (int nt = 0; nt < 4; ++nt) {
    const int nb = n0 + wn*64 + nt*16 + quad*4;
    const float4 bv = *(const float4*)&bias[nb];
#pragma unroll
    for (int mt = 0; mt < 4; ++mt) {
      const int m = m0 + wm*64 + mt*16 + col;
      const float v0 = (acc[mt][nt][0] + bv.x) * oscale;
      const float v1 = (acc[mt][nt][1] + bv.y) * oscale;
      const float v2 = (acc[mt][nt][2] + bv.z) * oscale;
      const float v3 = (acc[mt][nt][3] + bv.w) * oscale;
      if (!OUT_BF16) {
        float4 f4 = {v0, v1, v2, v3};
        *(float4*)&((float*)Out)[(size_t)m * D_ + nb] = f4;
      } else if (seg != 2) {
        uint2 w2 = make_uint2(pack2bf(v0, v1), pack2bf(v2, v3));
        *(uint2*)&((u16*)Out)[(size_t)m * D_ + nb] = w2;
      } else {
        // V: write transposed Vt[(b*16+h)*64+hd][t]
        const int bb = m >> 11, tt = m & 2047;
        const int h = nb >> 6, hd = nb & 63;
        u16* vp = (u16*)Out + ((size_t)((bb*16 + h)*64 + hd)) * 2048 + tt;
        vp[0]    = f2bf(v0);
        vp[2048] = f2bf(v1);
        vp[4096] = f2bf(v2);
        vp[6144] = f2bf(v3);
      }
    }
  }
}

// ---------------- Flash attention: dbuf-staged K/V, 128-row q-blocks ----------
// (frozen — control for this round)
__global__ __launch_bounds__(256) void attn_fwd(
    const u16* __restrict__ Qp, const u16* __restrict__ Kp,
    const u16* __restrict__ Vt, u16* __restrict__ Oout)
{
  __shared__ u16 Ks[2 * 4096];  // [buf][slot=hd/8][row=j][8]
  __shared__ u16 Vs[2 * 4096];  // [buf][slot=t/8][row=hd][8]
  __shared__ __align__(16) u16 plds[4 * 32 * 72];   // per-wave P, stride 72

  const int tid  = threadIdx.x;
  const int wave = tid >> 6;
  const int lane = tid & 63;
  const int col  = lane & 15;
  const int quad = lane >> 4;
  const int blk  = blockIdx.x;
  const int bh   = blk & 63;
  const int qt   = 15 - (blk >> 6);   // longest blocks first
  const int b = bh >> 4, h = bh & 15;
  const int rb0 = qt*128 + wave*16;   // group0 rows
  const int q0 = rb0 + col;
  const int q1 = q0 + 64;

  u16* const pl = plds + wave * 32 * 72;   // rows 0..15 grp0, 16..31 grp1

  bf16x8 qa0, qa1, qb0, qb1;
  {
    const u16* qr = Qp + (size_t)(b*T_ + q0) * D_ + h*HD_ + quad*8;
    qa0 = *(const bf16x8*)(qr);
    qa1 = *(const bf16x8*)(qr + 32);
    qr += (size_t)64 * D_;
    qb0 = *(const bf16x8*)(qr);
    qb1 = *(const bf16x8*)(qr + 32);
  }

  const u16* kbase = Kp + (size_t)(b*T_) * D_ + h*HD_;
  const u16* vbase = Vt + (size_t)(bh*HD_) * T_;

  const int srow  = tid & 63;
  const int sslot = tid >> 6;
  const u16* kg0 = kbase + (size_t)srow * D_ + sslot*8;
  const u16* kg1 = kbase + (size_t)srow * D_ + (4+sslot)*8;
  const u16* vg0 = vbase + (size_t)srow * T_ + sslot*8;
  const u16* vg1 = vbase + (size_t)srow * T_ + (4+sslot)*8;

  const f32x4 z = {0.f, 0.f, 0.f, 0.f};
  f32x4 oa[4], ob[4];
#pragma unroll
  for (int dt = 0; dt < 4; ++dt) { oa[dt] = z; ob[dt] = z; }
  f32x4 la = z, lb = z;

  const int jend0  = qt * 128;
  const int jend1  = qt * 128 + 64;
  const int ntiles = (jend1 >> 6) + 1;

  GLOAD_LDS16(kg0, Ks + tid*8);
  GLOAD_LDS16(kg1, Ks + 2048 + tid*8);
  GLOAD_LDS16(vg0, Vs + tid*8);
  GLOAD_LDS16(vg1, Vs + 2048 + tid*8);
  __syncthreads();

  int cur = 0;
  for (int t = 0; t < ntiles; ++t) {
    const int j0 = t << 6;

    if (t + 1 < ntiles) {
      const int jn = j0 + 64;
      const size_t kj = (size_t)jn * D_;
      u16* kb = Ks + (cur ^ 1) * 4096;
      u16* vb = Vs + (cur ^ 1) * 4096;
      GLOAD_LDS16(kg0 + kj, kb + tid*8);
      GLOAD_LDS16(kg1 + kj, kb + 2048 + tid*8);
      GLOAD_LDS16(vg0 + jn, vb + tid*8);
      GLOAD_LDS16(vg1 + jn, vb + 2048 + tid*8);
    }
    MEMBAR();

    const u16* kr = Ks + cur * 4096;
    const u16* vr = Vs + cur * 4096;

    f32x4 sa[4], sb[4];
    __builtin_amdgcn_s_setprio(1);
#pragma unroll
    for (int jt = 0; jt < 4; ++jt) {
      bf16x8 kf0 = *(const bf16x8*)(kr + (quad*64 + jt*16 + col) * 8);
      bf16x8 kf1 = *(const bf16x8*)(kr + 2048 + (quad*64 + jt*16 + col) * 8);
      sa[jt] = __builtin_amdgcn_mfma_f32_16x16x32_bf16(kf0, qa0, z, 0,0,0);
      sa[jt] = __builtin_amdgcn_mfma_f32_16x16x32_bf16(kf1, qa1, sa[jt], 0,0,0);
      sb[jt] = __builtin_amdgcn_mfma_f32_16x16x32_bf16(kf0, qb0, z, 0,0,0);
      sb[jt] = __builtin_amdgcn_mfma_f32_16x16x32_bf16(kf1, qb1, sb[jt], 0,0,0);
    }
    __builtin_amdgcn_s_setprio(0);

    if (j0 >= jend0) {
      const int dq = q0 - j0;
#pragma unroll
      for (int jt = 0; jt < 4; ++jt)
#pragma unroll
        for (int r = 0; r < 4; ++r) {
          const int jo = jt*16 + quad*4 + r;
          sa[jt][r] = (jo > dq) ? 0.f : __builtin_amdgcn_exp2f(sa[jt][r]);
        }
    } else {
#pragma unroll
      for (int jt = 0; jt < 4; ++jt)
#pragma unroll
        for (int r = 0; r < 4; ++r)
          sa[jt][r] = __builtin_amdgcn_exp2f(sa[jt][r]);
    }
    if (j0 >= jend1) {
      const int dq = q1 - j0;
#pragma unroll
      for (int jt = 0; jt < 4; ++jt)
#pragma unroll
        for (int r = 0; r < 4; ++r) {
          const int jo = jt*16 + quad*4 + r;
          sb[jt][r] = (jo > dq) ? 0.f : __builtin_amdgcn_exp2f(sb[jt][r]);
        }
    } else {
#pragma unroll
      for (int jt = 0; jt < 4; ++jt)
#pragma unroll
        for (int r = 0; r < 4; ++r)
          sb[jt][r] = __builtin_amdgcn_exp2f(sb[jt][r]);
    }
#pragma unroll
    for (int jt = 0; jt < 4; ++jt) { la += sa[jt]; lb += sb[jt]; }

    {
      u16* prow = pl + col * 72;
#pragma unroll
      for (int jt = 0; jt < 4; ++jt) {
        uint2 w2;
        w2.x = pack2bf(sa[jt][0], sa[jt][1]);
        w2.y = pack2bf(sa[jt][2], sa[jt][3]);
        *(uint2*)(prow + jt*16 + quad*4) = w2;
      }
      prow = pl + (16 + col) * 72;
#pragma unroll
      for (int jt = 0; jt < 4; ++jt) {
        uint2 w2;
        w2.x = pack2bf(sb[jt][0], sb[jt][1]);
        w2.y = pack2bf(sb[jt][2], sb[jt][3]);
        *(uint2*)(prow + jt*16 + quad*4) = w2;
      }
    }
    MEMBAR();

    {
      bf16x8 pa0 = *(const bf16x8*)(pl + col*72 + quad*8);
      bf16x8 pa1 = *(const bf16x8*)(pl + col*72 + 32 + quad*8);
      bf16x8 pb0 = *(const bf16x8*)(pl + (16+col)*72 + quad*8);
      bf16x8 pb1 = *(const bf16x8*)(pl + (16+col)*72 + 32 + quad*8);
      __builtin_amdgcn_s_setprio(1);
#pragma unroll
      for (int dt = 0; dt < 4; ++dt) {
        bf16x8 v0 = *(const bf16x8*)(vr + (quad*64 + dt*16 + col) * 8);
        bf16x8 v1 = *(const bf16x8*)(vr + 2048 + (quad*64 + dt*16 + col) * 8);
        oa[dt] = __builtin_amdgcn_mfma_f32_16x16x32_bf16(v0, pa0, oa[dt], 0,0,0);
        oa[dt] = __builtin_amdgcn_mfma_f32_16x16x32_bf16(v1, pa1, oa[dt], 0,0,0);
        ob[dt] = __builtin_amdgcn_mfma_f32_16x16x32_bf16(v0, pb0, ob[dt], 0,0,0);
        ob[dt] = __builtin_amdgcn_mfma_f32_16x16x32_bf16(v1, pb1, ob[dt], 0,0,0);
      }
      __builtin_amdgcn_s_setprio(0);
    }

    __syncthreads();
    cur ^= 1;
  }

  float l0 = (la[0] + la[1]) + (la[2] + la[3]);
  l0 += __shfl_xor(l0, 16);
  l0 += __shfl_xor(l0, 32);
  const float ra = __builtin_amdgcn_rcpf(l0);
  float l1 = (lb[0] + lb[1]) + (lb[2] + lb[3]);
  l1 += __shfl_xor(l1, 16);
  l1 += __shfl_xor(l1, 32);
  const float rb = __builtin_amdgcn_rcpf(l1);

  u16* orow = Oout + (size_t)(b*T_ + q0) * D_ + h*HD_;
#pragma unroll
  for (int dt = 0; dt < 4; ++dt) {
    uint2 w2;
    w2.x = pack2bf(oa[dt][0]*ra, oa[dt][1]*ra);
    w2.y = pack2bf(oa[dt][2]*ra, oa[dt][3]*ra);
    *(uint2*)(orow + dt*16 + quad*4) = w2;
  }
  orow += (size_t)64 * D_;
#pragma unroll
  for (int dt = 0; dt < 4; ++dt) {
    uint2 w2;
    w2.x = pack2bf(ob[dt][0]*rb, ob[dt][1]*rb);
    w2.y = pack2bf(ob[dt][2]*rb, ob[dt][3]*rb);
    *(uint2*)(orow + dt*16 + quad*4) = w2;
  }
}

// ------------------------------- launcher -------------------------------------
extern "C" void kernel_launch(void* const* d_in, const int* in_sizes, int n_in,
                              void* d_out, int out_size, void* d_ws, size_t ws_size,
                              hipStream_t stream) {
  const float* q  = (const float*)d_in[0];
  const float* k  = (const float*)d_in[1];
  const float* v  = (const float*)d_in[2];
  // d_in[3] = mask: causal tril, implemented analytically
  const float* Wq = (const float*)d_in[4];
  const float* bq = (const float*)d_in[5];
  const float* Wk = (const float*)d_in[6];
  const float* bk = (const float*)d_in[7];
  const float* Wv = (const float*)d_in[8];
  const float* bv = (const float*)d_in[9];
  const float* Wo = (const float*)d_in[10];
  const float* bo = (const float*)d_in[11];
  float* out = (float*)d_out;

  char* w = (char*)d_ws;
  const size_t SZ = (size_t)BT_ * D_ * sizeof(u16);   // 16 MiB per tensor
  u16* Xq = (u16*)(w + 0*SZ);         // q-act bf16; later attention output
  u16* Xk = (u16*)(w + 1*SZ);
  u16* Xv = (u16*)(w + 2*SZ);
  u16* Qp = (u16*)(w + 3*SZ);
  u16* Kp = (u16*)(w + 4*SZ);
  u16* Vt = (u16*)(w + 5*SZ);         // written transposed by gemm_big seg 2
  u16* Wbq = (u16*)(w + 6*SZ);
  u16* Wbk = (u16*)(w + 6*SZ + 1*(size_t)D_*D_*2);
  u16* Wbv = (u16*)(w + 6*SZ + 2*(size_t)D_*D_*2);
  u16* Wbo = (u16*)(w + 6*SZ + 3*(size_t)D_*D_*2);
  u16* AO = Xq;

  const int n4x = BT_ * D_ / 4;
  const int n4w = D_ * D_ / 4;
  const int cvx = n4x / 256, cvw = n4w / 256;
  const int attn_g = (B_*H_) * (T_/128);         // 1024 blocks, longest-first
  dim3 blk(256);
  dim3 blk512(512);

  // converts: activations (1 dispatch) + all weights (1 dispatch)
  cvt3_f32_bf16<<<3*cvx, blk, 0, stream>>>(q, k, v, Xq, Xk, Xv, cvx);
  cvt4_f32_bf16<<<4*cvw, blk, 0, stream>>>(Wq, Wk, Wv, Wo,
                                           Wbq, Wbk, Wbv, Wbo, cvw);
  // fused QKV projection (V written pre-transposed); 3 x 256 blocks
  gemm_big<true><<<768, blk512, 0, stream>>>(
      Xq, Xk, Xv, Wbq, Wbk, Wbv, bq, bk, bv, Qp, Kp, Vt, SFC);
  // attention
  attn_fwd<<<attn_g, blk, 0, stream>>>(Qp, Kp, Vt, AO);
  // output projection -> fp32 d_out (256 blocks, exactly 1/CU)
  gemm_big<false><<<256, blk512, 0, stream>>>(
      AO, AO, AO, Wbo, Wbo, Wbo, bo, bo, bo, (void*)out, (void*)out,
      (void*)out, 1.0f);
}

// Round 6
// 332.329 us; speedup vs baseline: 1.0217x; 1.0217x over previous
//
#include <hip/hip_runtime.h>

// Problem constants (B,T,D,H from reference)
#define B_  4
#define T_  2048
#define D_  1024
#define H_  16
#define HD_ 64
#define BT_ (B_*T_)   // 8192
#define K_  D_        // 1024 (GEMM inner dim)

typedef unsigned short u16;
typedef unsigned int   u32;

typedef __attribute__((ext_vector_type(8))) short bf16x8;  // 8 bf16 (4 VGPRs)
typedef __attribute__((ext_vector_type(4))) float f32x4;   // MFMA 16x16 C/D

__device__ __forceinline__ u16 f2bf(float f) {
  u32 u = __builtin_bit_cast(u32, f);
  u += 0x7fffu + ((u >> 16) & 1u);   // round-to-nearest-even
  return (u16)(u >> 16);
}

// packed f32x2 -> bf16x2 (RNE), single VALU op; D[15:0]=lo, D[31:16]=hi
__device__ __forceinline__ u32 cvtpk(float lo, float hi) {
  u32 r;
  __asm__("v_cvt_pk_bf16_f32 %0, %1, %2" : "=v"(r) : "v"(lo), "v"(hi));
  return r;
}

#define GLOAD_LDS16(g, l) __builtin_amdgcn_global_load_lds(                  \
    (const __attribute__((address_space(1))) void*)(g),                      \
    (__attribute__((address_space(3))) void*)(l), 16, 0, 0)

// compiler-only memory barrier: forbids IR reordering of LDS/global ops
#define MEMBAR() __asm__ volatile("" ::: "memory")
#define SCHEDB() __builtin_amdgcn_sched_barrier(0)
#define SBAR()   __builtin_amdgcn_s_barrier()

#define SFC 0.18033688011f   /* 0.125 * log2(e); folded into Q projection */

// ---------------- fp32 -> bf16 weight converts (4 matrices, 1 dispatch) -------
__global__ __launch_bounds__(256) void cvt4_f32_bf16(
    const float* __restrict__ i0, const float* __restrict__ i1,
    const float* __restrict__ i2, const float* __restrict__ i3,
    u16* __restrict__ o0, u16* __restrict__ o1,
    u16* __restrict__ o2, u16* __restrict__ o3, int cvw) {
  const int blk = blockIdx.x;
  const int seg = blk / cvw;           // 0..3
  const int ib  = blk - seg*cvw;
  const float* in = seg==0 ? i0 : (seg==1 ? i1 : (seg==2 ? i2 : i3));
  u16* out        = seg==0 ? o0 : (seg==1 ? o1 : (seg==2 ? o2 : o3));
  const int i = ib*256 + threadIdx.x;
  float4 x = ((const float4*)in)[i];
  u32 lo = (u32)f2bf(x.x) | ((u32)f2bf(x.y) << 16);
  u32 hi = (u32)f2bf(x.z) | ((u32)f2bf(x.w) << 16);
  ((uint2*)out)[i] = make_uint2(lo, hi);
}

// ---------------- GEMM: 128x128 tile, BK=32, counted pipeline -----------------
// QKV-fused: seg = blockIdx.x>>9 selects {A,W,bias,Out} (grid 1536 = 3x512).
// A is the RAW FP32 activation tensor: staged via registers (4 x float4 load ->
// v_cvt_pk_bf16_f32 -> 2 x ds_write_b128, same swizzled layout) — this absorbs
// the former cvt3 pass into the GEMM's idle latency (VALUBusy was 16%).
// B (weights) is bf16 (cvt4) via global_load_lds.
// Pipeline, ONE barrier per K-step:
//   top:  A-regloads(t+1), B-gload_lds(t+1) -> buf^1
//   mid:  ds_read frags(t) ; lgkmcnt(0) ; 16 MFMA (setprio)
//   end:  cvt+ds_write A(t+1) [compiler-counted vmcnt waits the aged regloads]
//         vmcnt(0) [B(t+1), aged through MFMA] ; lgkmcnt(0) ; s_barrier
// Slot swizzle (both sides): physical slot s of row r holds k-chunk
// s ^ ((r>>1)&3); frag ds_read applies the same XOR (2 lanes/4-bank group).
// MFMA operands swapped (W-frag first): lane regs hold 4 consecutive n.
// seg==2 writes V transposed to Vt[b,h,hd,t] (replaces transpose kernel).
__global__ __launch_bounds__(256, 4) void gemm_qkv(
    const float* __restrict__ A0, const float* __restrict__ A1,
    const float* __restrict__ A2,
    const u16* __restrict__ W0, const u16* __restrict__ W1,
    const u16* __restrict__ W2,
    const float* __restrict__ b0, const float* __restrict__ b1,
    const float* __restrict__ b2,
    u16* __restrict__ O0, u16* __restrict__ O1, u16* __restrict__ O2,
    float osc0)
{
  __shared__ u16 As[2][128 * 32];   // [buf][row][slot][8]
  __shared__ u16 Bs[2][128 * 32];

  const int tid  = threadIdx.x;
  const int wave = tid >> 6;
  const int lane = tid & 63;
  const int col  = lane & 15;
  const int quad = lane >> 4;
  const int wy   = wave >> 1;          // m-half (64)
  const int wx   = wave & 1;           // n-half (64)

  const int seg   = blockIdx.x >> 9;   // 0=Q 1=K 2=V
  const int inner = blockIdx.x & 511;
  const float* A   = seg==0 ? A0 : (seg==1 ? A1 : A2);
  const u16*   W   = seg==0 ? W0 : (seg==1 ? W1 : W2);
  const float* bias = seg==0 ? b0 : (seg==1 ? b1 : b2);
  u16*         Out = seg==0 ? O0 : (seg==1 ? O1 : O2);
  const float oscale = (seg == 0) ? osc0 : 1.0f;

  // XCD-clustered swizzle within the 512-block segment
  const int xcd = inner & 7;
  const int jj  = inner >> 3;          // 0..63
  const int m0 = (xcd*8 + (jj & 7)) * 128;
  const int n0 = (jj >> 3) * 128;

  // staging maps: 4 threads/row; physical slot tid&3 holds k-chunk
  // (tid&3)^((row>>1)&3).  (row+64)>>1 keeps &3 -> same map both halves.
  const int srow = tid >> 2;                           // 0..63
  const int kseg = ((tid & 3) ^ ((srow >> 1) & 3)) * 8;
  const float* agp = A + (size_t)(m0 + srow) * K_ + kseg;   // fp32 source
  const u16*   bgp = W + (size_t)(n0 + srow) * K_ + kseg;   // bf16 source

  f32x4 acc[4][4];
  const f32x4 z = {0.f, 0.f, 0.f, 0.f};
#pragma unroll
  for (int i = 0; i < 4; ++i)
#pragma unroll
    for (int j = 0; j < 4; ++j) acc[i][j] = z;

  // frag LDS offsets (u16): row*32 + (quad ^ ((row>>1)&3))*8
  u32 aro[4], bro[4];
#pragma unroll
  for (int i = 0; i < 4; ++i) {
    const int ar = wy*64 + i*16 + col;
    const int br = wx*64 + i*16 + col;
    aro[i] = (u32)(ar*32 + ((quad ^ ((ar >> 1) & 3)) * 8));
    bro[i] = (u32)(br*32 + ((quad ^ ((br >> 1) & 3)) * 8));
  }

  float4 ra0, ra1, ra2, ra3;                 // in-flight A rows (fp32)
#define LOADA(kn) {                                                          \
    ra0 = *(const float4*)(agp + (kn));                                      \
    ra1 = *(const float4*)(agp + (kn) + 4);                                  \
    ra2 = *(const float4*)(agp + (size_t)64*K_ + (kn));                      \
    ra3 = *(const float4*)(agp + (size_t)64*K_ + (kn) + 4); }
#define ISSB(buf, kn) {                                                      \
    GLOAD_LDS16(bgp + (kn),                 &Bs[buf][tid*8]);                \
    GLOAD_LDS16(bgp + (size_t)64*K_ + (kn), &Bs[buf][2048 + tid*8]); }
#define WRITEA(buf) {                                                        \
    uint4 q0 = { cvtpk(ra0.x, ra0.y), cvtpk(ra0.z, ra0.w),                   \
                 cvtpk(ra1.x, ra1.y), cvtpk(ra1.z, ra1.w) };                 \
    *(uint4*)(&As[buf][tid*8]) = q0;                                         \
    uint4 q1 = { cvtpk(ra2.x, ra2.y), cvtpk(ra2.z, ra2.w),                   \
                 cvtpk(ra3.x, ra3.y), cvtpk(ra3.z, ra3.w) };                 \
    *(uint4*)(&As[buf][2048 + tid*8]) = q1; }

  // prologue: tile 0 -> buf 0 (one-time full drain)
  LOADA(0); MEMBAR();
  ISSB(0, 0); MEMBAR();
  WRITEA(0);
  __asm__ volatile("s_waitcnt vmcnt(0)" ::: "memory");
  __asm__ volatile("s_waitcnt lgkmcnt(0)" ::: "memory");
  SCHEDB();
  SBAR();
  MEMBAR();

  int cur = 0;
  for (int t = 0; t < 32; ++t) {
    const int kn = (t + 1) * 32;
    const bool more = (t < 31);
    if (more) {
      LOADA(kn);            // fp32 regs; consumed after MFMA (aged)
      MEMBAR();
      ISSB(cur ^ 1, kn);    // bf16 W -> LDS direct
      MEMBAR();
    }
    SCHEDB();

    bf16x8 af[4], bfr[4];
#pragma unroll
    for (int i = 0; i < 4; ++i) af[i]  = *(const bf16x8*)(&As[cur][aro[i]]);
#pragma unroll
    for (int i = 0; i < 4; ++i) bfr[i] = *(const bf16x8*)(&Bs[cur][bro[i]]);
    __asm__ volatile("s_waitcnt lgkmcnt(0)" ::: "memory");
    SCHEDB();
    __builtin_amdgcn_s_setprio(1);
#pragma unroll
    for (int mt = 0; mt < 4; ++mt)
#pragma unroll
      for (int nt = 0; nt < 4; ++nt)
        acc[mt][nt] = __builtin_amdgcn_mfma_f32_16x16x32_bf16(
            bfr[nt], af[mt], acc[mt][nt], 0, 0, 0);   // swapped: regs = n-dim
    __builtin_amdgcn_s_setprio(0);
    SCHEDB();

    if (more) {
      WRITEA(cur ^ 1);      // compiler inserts counted vmcnt for ra0..ra3
      __asm__ volatile("s_waitcnt vmcnt(0)" ::: "memory");   // B(t+1) aged
    }
    __asm__ volatile("s_waitcnt lgkmcnt(0)" ::: "memory");   // ds_writes done
    SCHEDB();
    SBAR();                 // single barrier per K-step
    MEMBAR();
    cur ^= 1;
  }
#undef LOADA
#undef ISSB
#undef WRITEA

  // epilogue: lane holds 4 consecutive n per (mt,nt)
#pragma unroll
  for (int nt = 0; nt < 4; ++nt) {
    const int nb = n0 + wx*64 + nt*16 + quad*4;
    const float4 bv = *(const float4*)&bias[nb];
#pragma unroll
    for (int mt = 0; mt < 4; ++mt) {
      const int m = m0 + wy*64 + mt*16 + col;
      const float v0 = (acc[mt][nt][0] + bv.x) * oscale;
      const float v1 = (acc[mt][nt][1] + bv.y) * oscale;
      const float v2 = (acc[mt][nt][2] + bv.z) * oscale;
      const float v3 = (acc[mt][nt][3] + bv.w) * oscale;
      if (seg != 2) {
        uint2 w2 = make_uint2(cvtpk(v0, v1), cvtpk(v2, v3));
        *(uint2*)&Out[(size_t)m * D_ + nb] = w2;
      } else {
        // V: write transposed Vt[(b*16+h)*64+hd][t]
        const int bb = m >> 11, tt = m & 2047;
        const int h = nb >> 6, hd = nb & 63;
        u16* vp = Out + ((size_t)((bb*16 + h)*64 + hd)) * 2048 + tt;
        vp[0]    = f2bf(v0);
        vp[2048] = f2bf(v1);
        vp[4096] = f2bf(v2);
        vp[6144] = f2bf(v3);
      }
    }
  }
}

// ---------------- O-projection GEMM: 64x128 tile, grid 1024 -------------------
// (round-4 structure, frozen as control)
__global__ __launch_bounds__(256, 4) void gemm_o(
    const u16* __restrict__ A, const u16* __restrict__ W,
    const float* __restrict__ bias, float* __restrict__ Out)
{
  __shared__ u16 As[2][64 * 32];
  __shared__ u16 Bs[2][128 * 32];

  const int tid  = threadIdx.x;
  const int wave = tid >> 6;
  const int lane = tid & 63;
  const int col  = lane & 15;
  const int quad = lane >> 4;
  const int wy   = wave >> 1;          // m-half (32)
  const int wx   = wave & 1;           // n-half (64)

  const int xcd = blockIdx.x & 7;
  const int jj  = blockIdx.x >> 3;     // 0..127
  const int m0 = (xcd*16 + (jj & 15)) * 64;
  const int n0 = (jj >> 4) * 128;

  const int srow = tid >> 2;                           // 0..63
  const int kseg = ((tid & 3) ^ ((srow >> 1) & 3)) * 8;
  const u16* agp = A + (size_t)(m0 + srow) * K_ + kseg;
  const u16* bgp = W + (size_t)(n0 + srow) * K_ + kseg;

  f32x4 acc[2][4];
  const f32x4 z = {0.f, 0.f, 0.f, 0.f};
#pragma unroll
  for (int i = 0; i < 2; ++i)
#pragma unroll
    for (int j = 0; j < 4; ++j) acc[i][j] = z;

  u32 aro[2], bro[4];
#pragma unroll
  for (int i = 0; i < 2; ++i) {
    const int ar = wy*32 + i*16 + col;
    aro[i] = (u32)(ar*32 + ((quad ^ ((ar >> 1) & 3)) * 8));
  }
#pragma unroll
  for (int i = 0; i < 4; ++i) {
    const int br = wx*64 + i*16 + col;
    bro[i] = (u32)(br*32 + ((quad ^ ((br >> 1) & 3)) * 8));
  }

  auto STAGE = [&](int buf, int k0) {
    GLOAD_LDS16(agp + k0,                 &As[buf][tid*8]);
    GLOAD_LDS16(bgp + k0,                 &Bs[buf][tid*8]);
    GLOAD_LDS16(bgp + (size_t)64*K_ + k0, &Bs[buf][2048 + tid*8]);
  };

  STAGE(0, 0);
  MEMBAR();

  int cur = 0;
  for (int k0 = 0; k0 < K_; k0 += 32) {
    if (k0 + 32 < K_) {
      STAGE(cur ^ 1, k0 + 32);    // prefetch next K-slice (3 loads/wave)
      MEMBAR();
      __asm__ volatile("s_waitcnt vmcnt(3)" ::: "memory");
    } else {
      __asm__ volatile("s_waitcnt vmcnt(0)" ::: "memory");
    }
    SCHEDB();
    SBAR();
    MEMBAR();
    SCHEDB();

    bf16x8 af[2], bfr[4];
#pragma unroll
    for (int i = 0; i < 2; ++i) af[i]  = *(const bf16x8*)(&As[cur][aro[i]]);
#pragma unroll
    for (int i = 0; i < 4; ++i) bfr[i] = *(const bf16x8*)(&Bs[cur][bro[i]]);
    __asm__ volatile("s_waitcnt lgkmcnt(0)" ::: "memory");
    SCHEDB();
#pragma unroll
    for (int mt = 0; mt < 2; ++mt)
#pragma unroll
      for (int nt = 0; nt < 4; ++nt)
        acc[mt][nt] = __builtin_amdgcn_mfma_f32_16x16x32_bf16(
            bfr[nt], af[mt], acc[mt][nt], 0, 0, 0);

    SCHEDB();
    SBAR();
    MEMBAR();
    SCHEDB();
    cur ^= 1;
  }

#pragma unroll
  for (int nt = 0; nt < 4; ++nt) {
    const int nb = n0 + wx*64 + nt*16 + quad*4;
    const float4 bv = *(const float4*)&bias[nb];
#pragma unroll
    for (int mt = 0; mt < 2; ++mt) {
      const int m = m0 + wy*32 + mt*16 + col;
      float4 f4 = {acc[mt][nt][0] + bv.x, acc[mt][nt][1] + bv.y,
                   acc[mt][nt][2] + bv.z, acc[mt][nt][3] + bv.w};
      *(float4*)&Out[(size_t)m * D_ + nb] = f4;
    }
  }
}

// ---------------- Flash attention: dbuf-staged K/V, 128-row q-blocks ----------
// (structure frozen; only pack2bf -> v_cvt_pk_bf16_f32, 4 VALU ops -> 1)
__global__ __launch_bounds__(256) void attn_fwd(
    const u16* __restrict__ Qp, const u16* __restrict__ Kp,
    const u16* __restrict__ Vt, u16* __restrict__ Oout)
{
  __shared__ u16 Ks[2 * 4096];  // [buf][slot=hd/8][row=j][8]
  __shared__ u16 Vs[2 * 4096];  // [buf][slot=t/8][row=hd][8]
  __shared__ __align__(16) u16 plds[4 * 32 * 72];   // per-wave P, stride 72

  const int tid  = threadIdx.x;
  const int wave = tid >> 6;
  const int lane = tid & 63;
  const int col  = lane & 15;
  const int quad = lane >> 4;
  const int blk  = blockIdx.x;
  const int bh   = blk & 63;
  const int qt   = 15 - (blk >> 6);   // longest blocks first
  const int b = bh >> 4, h = bh & 15;
  const int rb0 = qt*128 + wave*16;   // group0 rows
  const int q0 = rb0 + col;
  const int q1 = q0 + 64;

  u16* const pl = plds + wave * 32 * 72;   // rows 0..15 grp0, 16..31 grp1

  bf16x8 qa0, qa1, qb0, qb1;
  {
    const u16* qr = Qp + (size_t)(b*T_ + q0) * D_ + h*HD_ + quad*8;
    qa0 = *(const bf16x8*)(qr);
    qa1 = *(const bf16x8*)(qr + 32);
    qr += (size_t)64 * D_;
    qb0 = *(const bf16x8*)(qr);
    qb1 = *(const bf16x8*)(qr + 32);
  }

  const u16* kbase = Kp + (size_t)(b*T_) * D_ + h*HD_;
  const u16* vbase = Vt + (size_t)(bh*HD_) * T_;

  const int srow  = tid & 63;
  const int sslot = tid >> 6;
  const u16* kg0 = kbase + (size_t)srow * D_ + sslot*8;
  const u16* kg1 = kbase + (size_t)srow * D_ + (4+sslot)*8;
  const u16* vg0 = vbase + (size_t)srow * T_ + sslot*8;
  const u16* vg1 = vbase + (size_t)srow * T_ + (4+sslot)*8;

  const f32x4 z = {0.f, 0.f, 0.f, 0.f};
  f32x4 oa[4], ob[4];
#pragma unroll
  for (int dt = 0; dt < 4; ++dt) { oa[dt] = z; ob[dt] = z; }
  f32x4 la = z, lb = z;

  const int jend0  = qt * 128;
  const int jend1  = qt * 128 + 64;
  const int ntiles = (jend1 >> 6) + 1;

  GLOAD_LDS16(kg0, Ks + tid*8);
  GLOAD_LDS16(kg1, Ks + 2048 + tid*8);
  GLOAD_LDS16(vg0, Vs + tid*8);
  GLOAD_LDS16(vg1, Vs + 2048 + tid*8);
  __syncthreads();

  int cur = 0;
  for (int t = 0; t < ntiles; ++t) {
    const int j0 = t << 6;

    if (t + 1 < ntiles) {
      const int jn = j0 + 64;
      const size_t kj = (size_t)jn * D_;
      u16* kb = Ks + (cur ^ 1) * 4096;
      u16* vb = Vs + (cur ^ 1) * 4096;
      GLOAD_LDS16(kg0 + kj, kb + tid*8);
      GLOAD_LDS16(kg1 + kj, kb + 2048 + tid*8);
      GLOAD_LDS16(vg0 + jn, vb + tid*8);
      GLOAD_LDS16(vg1 + jn, vb + 2048 + tid*8);
    }
    MEMBAR();

    const u16* kr = Ks + cur * 4096;
    const u16* vr = Vs + cur * 4096;

    f32x4 sa[4], sb[4];
    __builtin_amdgcn_s_setprio(1);
#pragma unroll
    for (int jt = 0; jt < 4; ++jt) {
      bf16x8 kf0 = *(const bf16x8*)(kr + (quad*64 + jt*16 + col) * 8);
      bf16x8 kf1 = *(const bf16x8*)(kr + 2048 + (quad*64 + jt*16 + col) * 8);
      sa[jt] = __builtin_amdgcn_mfma_f32_16x16x32_bf16(kf0, qa0, z, 0,0,0);
      sa[jt] = __builtin_amdgcn_mfma_f32_16x16x32_bf16(kf1, qa1, sa[jt], 0,0,0);
      sb[jt] = __builtin_amdgcn_mfma_f32_16x16x32_bf16(kf0, qb0, z, 0,0,0);
      sb[jt] = __builtin_amdgcn_mfma_f32_16x16x32_bf16(kf1, qb1, sb[jt], 0,0,0);
    }
    __builtin_amdgcn_s_setprio(0);

    if (j0 >= jend0) {
      const int dq = q0 - j0;
#pragma unroll
      for (int jt = 0; jt < 4; ++jt)
#pragma unroll
        for (int r = 0; r < 4; ++r) {
          const int jo = jt*16 + quad*4 + r;
          sa[jt][r] = (jo > dq) ? 0.f : __builtin_amdgcn_exp2f(sa[jt][r]);
        }
    } else {
#pragma unroll
      for (int jt = 0; jt < 4; ++jt)
#pragma unroll
        for (int r = 0; r < 4; ++r)
          sa[jt][r] = __builtin_amdgcn_exp2f(sa[jt][r]);
    }
    if (j0 >= jend1) {
      const int dq = q1 - j0;
#pragma unroll
      for (int jt = 0; jt < 4; ++jt)
#pragma unroll
        for (int r = 0; r < 4; ++r) {
          const int jo = jt*16 + quad*4 + r;
          sb[jt][r] = (jo > dq) ? 0.f : __builtin_amdgcn_exp2f(sb[jt][r]);
        }
    } else {
#pragma unroll
      for (int jt = 0; jt < 4; ++jt)
#pragma unroll
        for (int r = 0; r < 4; ++r)
          sb[jt][r] = __builtin_amdgcn_exp2f(sb[jt][r]);
    }
#pragma unroll
    for (int jt = 0; jt < 4; ++jt) { la += sa[jt]; lb += sb[jt]; }

    {
      u16* prow = pl + col * 72;
#pragma unroll
      for (int jt = 0; jt < 4; ++jt) {
        uint2 w2;
        w2.x = cvtpk(sa[jt][0], sa[jt][1]);
        w2.y = cvtpk(sa[jt][2], sa[jt][3]);
        *(uint2*)(prow + jt*16 + quad*4) = w2;
      }
      prow = pl + (16 + col) * 72;
#pragma unroll
      for (int jt = 0; jt < 4; ++jt) {
        uint2 w2;
        w2.x = cvtpk(sb[jt][0], sb[jt][1]);
        w2.y = cvtpk(sb[jt][2], sb[jt][3]);
        *(uint2*)(prow + jt*16 + quad*4) = w2;
      }
    }
    MEMBAR();

    {
      bf16x8 pa0 = *(const bf16x8*)(pl + col*72 + quad*8);
      bf16x8 pa1 = *(const bf16x8*)(pl + col*72 + 32 + quad*8);
      bf16x8 pb0 = *(const bf16x8*)(pl + (16+col)*72 + quad*8);
      bf16x8 pb1 = *(const bf16x8*)(pl + (16+col)*72 + 32 + quad*8);
      __builtin_amdgcn_s_setprio(1);
#pragma unroll
      for (int dt = 0; dt < 4; ++dt) {
        bf16x8 v0 = *(const bf16x8*)(vr + (quad*64 + dt*16 + col) * 8);
        bf16x8 v1 = *(const bf16x8*)(vr + 2048 + (quad*64 + dt*16 + col) * 8);
        oa[dt] = __builtin_amdgcn_mfma_f32_16x16x32_bf16(v0, pa0, oa[dt], 0,0,0);
        oa[dt] = __builtin_amdgcn_mfma_f32_16x16x32_bf16(v1, pa1, oa[dt], 0,0,0);
        ob[dt] = __builtin_amdgcn_mfma_f32_16x16x32_bf16(v0, pb0, ob[dt], 0,0,0);
        ob[dt] = __builtin_amdgcn_mfma_f32_16x16x32_bf16(v1, pb1, ob[dt], 0,0,0);
      }
      __builtin_amdgcn_s_setprio(0);
    }

    __syncthreads();
    cur ^= 1;
  }

  float l0 = (la[0] + la[1]) + (la[2] + la[3]);
  l0 += __shfl_xor(l0, 16);
  l0 += __shfl_xor(l0, 32);
  const float ra = __builtin_amdgcn_rcpf(l0);
  float l1 = (lb[0] + lb[1]) + (lb[2] + lb[3]);
  l1 += __shfl_xor(l1, 16);
  l1 += __shfl_xor(l1, 32);
  const float rb = __builtin_amdgcn_rcpf(l1);

  u16* orow = Oout + (size_t)(b*T_ + q0) * D_ + h*HD_;
#pragma unroll
  for (int dt = 0; dt < 4; ++dt) {
    uint2 w2;
    w2.x = cvtpk(oa[dt][0]*ra, oa[dt][1]*ra);
    w2.y = cvtpk(oa[dt][2]*ra, oa[dt][3]*ra);
    *(uint2*)(orow + dt*16 + quad*4) = w2;
  }
  orow += (size_t)64 * D_;
#pragma unroll
  for (int dt = 0; dt < 4; ++dt) {
    uint2 w2;
    w2.x = cvtpk(ob[dt][0]*rb, ob[dt][1]*rb);
    w2.y = cvtpk(ob[dt][2]*rb, ob[dt][3]*rb);
    *(uint2*)(orow + dt*16 + quad*4) = w2;
  }
}

// ------------------------------- launcher -------------------------------------
extern "C" void kernel_launch(void* const* d_in, const int* in_sizes, int n_in,
                              void* d_out, int out_size, void* d_ws, size_t ws_size,
                              hipStream_t stream) {
  const float* q  = (const float*)d_in[0];
  const float* k  = (const float*)d_in[1];
  const float* v  = (const float*)d_in[2];
  // d_in[3] = mask: causal tril, implemented analytically
  const float* Wq = (const float*)d_in[4];
  const float* bq = (const float*)d_in[5];
  const float* Wk = (const float*)d_in[6];
  const float* bk = (const float*)d_in[7];
  const float* Wv = (const float*)d_in[8];
  const float* bv = (const float*)d_in[9];
  const float* Wo = (const float*)d_in[10];
  const float* bo = (const float*)d_in[11];
  float* out = (float*)d_out;

  char* w = (char*)d_ws;
  const size_t SZ = (size_t)BT_ * D_ * sizeof(u16);   // 16 MiB per tensor
  // workspace: 4x16 MiB + 4x2 MiB = 72 MiB
  u16* Qp = (u16*)(w + 0*SZ);
  u16* Kp = (u16*)(w + 1*SZ);
  u16* Vt = (u16*)(w + 2*SZ);         // written transposed by gemm_qkv seg 2
  u16* AO = (u16*)(w + 3*SZ);         // attention output (bf16)
  u16* Wbq = (u16*)(w + 4*SZ);
  u16* Wbk = (u16*)(w + 4*SZ + 1*(size_t)D_*D_*2);
  u16* Wbv = (u16*)(w + 4*SZ + 2*(size_t)D_*D_*2);
  u16* Wbo = (u16*)(w + 4*SZ + 3*(size_t)D_*D_*2);

  const int n4w = D_ * D_ / 4;
  const int cvw = n4w / 256;
  const int attn_g = (B_*H_) * (T_/128);         // 1024 blocks, longest-first
  dim3 blk(256);

  // weights -> bf16 (1 dispatch); activations converted inside gemm_qkv
  cvt4_f32_bf16<<<4*cvw, blk, 0, stream>>>(Wq, Wk, Wv, Wo,
                                           Wbq, Wbk, Wbv, Wbo, cvw);
  // fused QKV projection, fp32 A staged+converted in-kernel
  gemm_qkv<<<1536, blk, 0, stream>>>(
      q, k, v, Wbq, Wbk, Wbv, bq, bk, bv, Qp, Kp, Vt, SFC);
  // attention
  attn_fwd<<<attn_g, blk, 0, stream>>>(Qp, Kp, Vt, AO);
  // output projection -> fp32 d_out
  gemm_o<<<1024, blk, 0, stream>>>(AO, Wbo, bo, out);
}